// Round 1
// 6976.128 us; speedup vs baseline: 1.8718x; 1.8718x over previous
//
#include <hip/hip_runtime.h>
#include <math.h>

// Round 1 rewrite: bf16x3 split-precision MFMA GEMMs (no LDS staging, register
// software pipeline), fused softmax/argmax partials in k_logits (logits tensor
// never hits global memory), tiny k_sample.
//
// ws layout (float offsets), total ~2.8 MB:
//   H0 0  H1 65536  GI 131072  GH 327680
//   PM 524288 PS 540288 AS 556288 AL 572288 AI 588288   (250*64 each)
//   HHI 604288 HLO 637056 (u16 64x1024)  XHI 669824 XLO 686208 (u16 64x512)

#define NBATCH 64
#define EMBD   512
#define HIDD   1024
#define NVOC   32000
#define SEQL   64
#define VROWS  128          // vocab rows per k_logits block
#define NLB    250          // NVOC / VROWS
#define GROWS  64           // gate rows per k_gates block
#define NGB    48           // 3072 / GROWS

typedef unsigned int   uint32;
typedef unsigned short u16;
typedef __attribute__((ext_vector_type(8))) short bf16x8;   // 8 bf16 (4 VGPR)
typedef __attribute__((ext_vector_type(4))) float f32x4;

// ---- fp32 -> (bf16 hi RNE, bf16 lo) split ------------------------------
__device__ __forceinline__ void split_pair(float x, float y, uint32& hi, uint32& lo) {
    uint32 a = __float_as_uint(x), b = __float_as_uint(y);
    uint32 ra = a + 0x7fffu + ((a >> 16) & 1u);
    uint32 rb = b + 0x7fffu + ((b >> 16) & 1u);
    hi = (ra >> 16) | (rb & 0xffff0000u);
    float lx = x - __uint_as_float(ra & 0xffff0000u);   // exact
    float ly = y - __uint_as_float(rb & 0xffff0000u);   // exact
    lo = (__float_as_uint(lx) >> 16) | (__float_as_uint(ly) & 0xffff0000u);
}

__device__ __forceinline__ void split8(const float4 f0, const float4 f1,
                                       bf16x8& hi, bf16x8& lo) {
    union { bf16x8 v; uint32 u[4]; } H, L;
    split_pair(f0.x, f0.y, H.u[0], L.u[0]);
    split_pair(f0.z, f0.w, H.u[1], L.u[1]);
    split_pair(f1.x, f1.y, H.u[2], L.u[2]);
    split_pair(f1.z, f1.w, H.u[3], L.u[3]);
    hi = H.v; lo = L.v;
}

__device__ __forceinline__ void split_scalar(float f, u16& hi, u16& lo) {
    uint32 u = __float_as_uint(f);
    uint32 r = u + 0x7fffu + ((u >> 16) & 1u);
    hi = (u16)(r >> 16);
    float lf = f - __uint_as_float(r & 0xffff0000u);
    uint32 ul = __float_as_uint(lf);
    uint32 rl = ul + 0x7fffu + ((ul >> 16) & 1u);
    lo = (u16)(rl >> 16);
}

// ---- B-operand fragments: lane l holds B[k=(l>>4)*8 + r][col=l&15] -----
// stored [b][K] bf16 -> contiguous 16B per lane.
__device__ __forceinline__ void load_b4(const u16* __restrict__ Bh,
                                        const u16* __restrict__ Bl,
                                        int K, int kk, int ll,
                                        bf16x8* bh, bf16x8* bl) {
#pragma unroll
    for (int tc = 0; tc < 4; ++tc) {
        size_t off = (size_t)(tc * 16 + ll) * K + kk;
        bh[tc] = *(const bf16x8*)(Bh + off);
        bl[tc] = *(const bf16x8*)(Bl + off);
    }
}

// D += Ahi*Bhi + Ahi*Blo + Alo*Bhi   over 4 column tiles
__device__ __forceinline__ void mfma3x4(const bf16x8 ahi, const bf16x8 alo,
                                        const bf16x8* bh, const bf16x8* bl,
                                        f32x4* acc) {
#pragma unroll
    for (int tc = 0; tc < 4; ++tc)
        acc[tc] = __builtin_amdgcn_mfma_f32_16x16x32_bf16(ahi, bh[tc], acc[tc], 0, 0, 0);
#pragma unroll
    for (int tc = 0; tc < 4; ++tc)
        acc[tc] = __builtin_amdgcn_mfma_f32_16x16x32_bf16(ahi, bl[tc], acc[tc], 0, 0, 0);
#pragma unroll
    for (int tc = 0; tc < 4; ++tc)
        acc[tc] = __builtin_amdgcn_mfma_f32_16x16x32_bf16(alo, bh[tc], acc[tc], 0, 0, 0);
}

// ---- init: h=0, x = emb[0] (split) -------------------------------------
__global__ __launch_bounds__(256) void k_init(const float* __restrict__ emb,
                                              float* __restrict__ h0,
                                              u16* __restrict__ hhi, u16* __restrict__ hlo,
                                              u16* __restrict__ xhi, u16* __restrict__ xlo) {
    int b = blockIdx.x, tid = threadIdx.x;
    for (int j = tid; j < HIDD; j += 256) {
        h0[b * HIDD + j] = 0.f; hhi[b * HIDD + j] = 0; hlo[b * HIDD + j] = 0;
    }
    for (int k = tid; k < EMBD; k += 256) {
        u16 h_, l_; split_scalar(emb[k], h_, l_);
        xhi[b * EMBD + k] = h_; xlo[b * EMBD + k] = l_;
    }
}

// ---- gates: out[n][b] = W[n]·X[b] + bias[n]  (64 rows/block, 4 waves) --
__global__ __launch_bounds__(256) void k_gates(
    const float* __restrict__ w_ih, const float* __restrict__ b_ih,
    const u16* __restrict__ xhi, const u16* __restrict__ xlo, float* __restrict__ gi,
    const float* __restrict__ w_hh, const float* __restrict__ b_hh,
    const u16* __restrict__ hhi, const u16* __restrict__ hlo, float* __restrict__ gh) {
    const float* W; const float* bias; const u16* Bh; const u16* Bl; float* out; int K;
    if (blockIdx.y == 0) { W = w_ih; bias = b_ih; Bh = xhi; Bl = xlo; out = gi; K = EMBD; }
    else                 { W = w_hh; bias = b_hh; Bh = hhi; Bl = hlo; out = gh; K = HIDD; }
    const int tid = threadIdx.x, wv = tid >> 6, l = tid & 63, lg = l >> 4, ll = l & 15;
    const int rbase = blockIdx.x * GROWS + wv * 16;
    const float* wrow = W + (size_t)(rbase + ll) * K;
    const int kl = lg * 8;

    f32x4 acc[4] = {};
    bf16x8 bhA[4], blA[4], bhB[4], blB[4], ahi, alo;
    float4 faA0, faA1, faB0, faB1;

    load_b4(Bh, Bl, K, kl, ll, bhA, blA);
    faA0 = *(const float4*)(wrow + kl);
    faA1 = *(const float4*)(wrow + kl + 4);
    for (int k = 0; k < K; k += 64) {
        load_b4(Bh, Bl, K, k + 32 + kl, ll, bhB, blB);
        faB0 = *(const float4*)(wrow + k + 32 + kl);
        faB1 = *(const float4*)(wrow + k + 32 + kl + 4);
        split8(faA0, faA1, ahi, alo);
        mfma3x4(ahi, alo, bhA, blA, acc);
        if (k + 64 < K) {
            load_b4(Bh, Bl, K, k + 64 + kl, ll, bhA, blA);
            faA0 = *(const float4*)(wrow + k + 64 + kl);
            faA1 = *(const float4*)(wrow + k + 64 + kl + 4);
        }
        split8(faB0, faB1, ahi, alo);
        mfma3x4(ahi, alo, bhB, blB, acc);
    }
#pragma unroll
    for (int j = 0; j < 4; ++j) {
        int n = rbase + lg * 4 + j;
        float bi = bias[n];
#pragma unroll
        for (int tc = 0; tc < 4; ++tc)
            out[n * 64 + tc * 16 + ll] = acc[tc][j] + bi;
    }
}

// ---- GRU elementwise + h split -----------------------------------------
__global__ __launch_bounds__(256) void k_gru(
    const float* __restrict__ gi, const float* __restrict__ gh,
    const float* __restrict__ h_in, float* __restrict__ h_out,
    u16* __restrict__ hhi, u16* __restrict__ hlo) {
    int tid = blockIdx.x * 256 + threadIdx.x;
    int b = tid & 63, j = tid >> 6;
    float ir = gi[j * 64 + b], iz = gi[(j + 1024) * 64 + b], in_ = gi[(j + 2048) * 64 + b];
    float hr = gh[j * 64 + b], hz = gh[(j + 1024) * 64 + b], hn = gh[(j + 2048) * 64 + b];
    float h = h_in[b * HIDD + j];
    float r = 1.f / (1.f + expf(-(ir + hr)));
    float z = 1.f / (1.f + expf(-(iz + hz)));
    float n = tanhf(in_ + r * hn);
    float hnew = (1.f - z) * n + z * h;
    h_out[b * HIDD + j] = hnew;
    u16 h_, l_; split_scalar(hnew, h_, l_);
    hhi[b * HIDD + j] = h_; hlo[b * HIDD + j] = l_;
}

// ---- logits GEMM + fused per-block softmax/argmax partials -------------
__global__ __launch_bounds__(256) void k_logits(
    const float* __restrict__ w_out, const float* __restrict__ b_out,
    const u16* __restrict__ hhi, const u16* __restrict__ hlo,
    const float* __restrict__ gum, const float* __restrict__ eps,
    float* __restrict__ pm, float* __restrict__ ps,
    float* __restrict__ as_, int* __restrict__ ai, float* __restrict__ al,
    int t) {
    const int tid = threadIdx.x, wv = tid >> 6, l = tid & 63, lg = l >> 4, ll = l & 15;
    const int v0 = blockIdx.x * VROWS;
    const int rb = v0 + wv * 32;
    const float* wrow0 = w_out + (size_t)(rb + ll) * HIDD;
    const float* wrow1 = w_out + (size_t)(rb + 16 + ll) * HIDD;
    const int kl = lg * 8;

    f32x4 acc[2][4] = {};
    bf16x8 bhA[4], blA[4], bhB[4], blB[4], ahi, alo;
    float4 fA[2][2], fB[2][2];

    load_b4(hhi, hlo, HIDD, kl, ll, bhA, blA);
    fA[0][0] = *(const float4*)(wrow0 + kl); fA[0][1] = *(const float4*)(wrow0 + kl + 4);
    fA[1][0] = *(const float4*)(wrow1 + kl); fA[1][1] = *(const float4*)(wrow1 + kl + 4);
    for (int k = 0; k < HIDD; k += 64) {
        const int k1 = k + 32 + kl;
        load_b4(hhi, hlo, HIDD, k1, ll, bhB, blB);
        fB[0][0] = *(const float4*)(wrow0 + k1); fB[0][1] = *(const float4*)(wrow0 + k1 + 4);
        fB[1][0] = *(const float4*)(wrow1 + k1); fB[1][1] = *(const float4*)(wrow1 + k1 + 4);
        split8(fA[0][0], fA[0][1], ahi, alo); mfma3x4(ahi, alo, bhA, blA, acc[0]);
        split8(fA[1][0], fA[1][1], ahi, alo); mfma3x4(ahi, alo, bhA, blA, acc[1]);
        if (k + 64 < HIDD) {
            const int k2 = k + 64 + kl;
            load_b4(hhi, hlo, HIDD, k2, ll, bhA, blA);
            fA[0][0] = *(const float4*)(wrow0 + k2); fA[0][1] = *(const float4*)(wrow0 + k2 + 4);
            fA[1][0] = *(const float4*)(wrow1 + k2); fA[1][1] = *(const float4*)(wrow1 + k2 + 4);
        }
        split8(fB[0][0], fB[0][1], ahi, alo); mfma3x4(ahi, alo, bhB, blB, acc[0]);
        split8(fB[1][0], fB[1][1], ahi, alo); mfma3x4(ahi, alo, bhB, blB, acc[1]);
    }

    // vals[tr][tc][j] : row = rb + tr*16 + lg*4 + j, col(b) = tc*16 + ll
    float val[2][4][4];
#pragma unroll
    for (int tr = 0; tr < 2; ++tr)
#pragma unroll
        for (int j = 0; j < 4; ++j) {
            float bo = b_out[rb + tr * 16 + lg * 4 + j];
#pragma unroll
            for (int tc = 0; tc < 4; ++tc) val[tr][tc][j] = acc[tr][tc][j] + bo;
        }

    // prefetch gumbel (HBM) early to hide latency under the reductions
    bool draw[4];
    float4 g4[2][4];
#pragma unroll
    for (int tc = 0; tc < 4; ++tc) {
        int b = tc * 16 + ll;
        draw[tc] = eps[t * 64 + b] <= 0.5f;
#pragma unroll
        for (int tr = 0; tr < 2; ++tr)
            g4[tr][tc] = *(const float4*)(gum + ((size_t)t * 64 + b) * NVOC + rb + tr * 16 + lg * 4);
    }

    __shared__ float sred[4][64];
    __shared__ float sred2[4][64];
    __shared__ int   sredi[4][64];
    __shared__ float sbm[64];

    // phase 1: block max per column b
    float lm[4];
#pragma unroll
    for (int tc = 0; tc < 4; ++tc) {
        float m = val[0][tc][0];
#pragma unroll
        for (int tr = 0; tr < 2; ++tr)
#pragma unroll
            for (int j = 0; j < 4; ++j) m = fmaxf(m, val[tr][tc][j]);
        m = fmaxf(m, __shfl_xor(m, 16));
        m = fmaxf(m, __shfl_xor(m, 32));
        lm[tc] = m;
    }
    if (l < 16) {
#pragma unroll
        for (int tc = 0; tc < 4; ++tc) sred[wv][tc * 16 + l] = lm[tc];
    }
    __syncthreads();
    if (tid < 64) {
        float m = fmaxf(fmaxf(sred[0][tid], sred[1][tid]), fmaxf(sred[2][tid], sred[3][tid]));
        sbm[tid] = m;
        pm[blockIdx.x * 64 + tid] = m;
    }
    __syncthreads();

    // phase 2: sum exp(val - blockmax)
#pragma unroll
    for (int tc = 0; tc < 4; ++tc) {
        float bm = sbm[tc * 16 + ll];
        float s = 0.f;
#pragma unroll
        for (int tr = 0; tr < 2; ++tr)
#pragma unroll
            for (int j = 0; j < 4; ++j) s += expf(val[tr][tc][j] - bm);
        s += __shfl_xor(s, 16);
        s += __shfl_xor(s, 32);
        lm[tc] = s;
    }
    if (l < 16) {
#pragma unroll
        for (int tc = 0; tc < 4; ++tc) sred[wv][tc * 16 + l] = lm[tc];
    }
    __syncthreads();
    if (tid < 64)
        ps[blockIdx.x * 64 + tid] = sred[0][tid] + sred[1][tid] + sred[2][tid] + sred[3][tid];

    // phase 3: partial gumbel argmax (score, idx, logit); lowest idx on ties
    const float LOGV = logf(32000.0f);
    float bsc[4]; int bix[4]; float blg[4];
#pragma unroll
    for (int tc = 0; tc < 4; ++tc) {
        float bs = -INFINITY; int bi = 0x7fffffff; float bl = 0.f;
#pragma unroll
        for (int tr = 0; tr < 2; ++tr) {
            const float* gp = (const float*)&g4[tr][tc];
#pragma unroll
            for (int j = 0; j < 4; ++j) {
                float u = fminf(fmaxf(gp[j], 1e-12f), 1.0f);
                float g = -logf(-logf(u));
                float sc = draw[tc] ? (g - LOGV) : (val[tr][tc][j] + g);
                if (sc > bs) { bs = sc; bi = rb + tr * 16 + lg * 4 + j; bl = val[tr][tc][j]; }
            }
        }
#pragma unroll
        for (int m2 = 16; m2 <= 32; m2 <<= 1) {
            float os = __shfl_xor(bs, m2);
            int   oi = __shfl_xor(bi, m2);
            float ol = __shfl_xor(bl, m2);
            if (os > bs || (os == bs && oi < bi)) { bs = os; bi = oi; bl = ol; }
        }
        bsc[tc] = bs; bix[tc] = bi; blg[tc] = bl;
    }
    __syncthreads();
    if (l < 16) {
#pragma unroll
        for (int tc = 0; tc < 4; ++tc) {
            sred[wv][tc * 16 + l]  = bsc[tc];
            sredi[wv][tc * 16 + l] = bix[tc];
            sred2[wv][tc * 16 + l] = blg[tc];
        }
    }
    __syncthreads();
    if (tid < 64) {
        float bs = sred[0][tid]; int bi = sredi[0][tid]; float bl = sred2[0][tid];
#pragma unroll
        for (int w2 = 1; w2 < 4; ++w2) {
            float os = sred[w2][tid]; int oi = sredi[w2][tid];
            if (os > bs || (os == bs && oi < bi)) { bs = os; bi = oi; bl = sred2[w2][tid]; }
        }
        as_[blockIdx.x * 64 + tid] = bs;
        ai[blockIdx.x * 64 + tid]  = bi;
        al[blockIdx.x * 64 + tid]  = bl;
    }
}

// ---- final reduce over 250 partials + outputs + emb gather/split -------
__global__ __launch_bounds__(256) void k_sample(
    const float* __restrict__ pm, const float* __restrict__ ps,
    const float* __restrict__ as_, const int* __restrict__ ai, const float* __restrict__ al,
    const float* __restrict__ emb, const float* __restrict__ eps,
    u16* __restrict__ xhi, u16* __restrict__ xlo,
    float* __restrict__ out, int t) {
    int b = blockIdx.x, tid = threadIdx.x;
    __shared__ float sv[256];
    __shared__ int   si_[256];
    __shared__ float sl[256];

    float m = (tid < NLB) ? pm[tid * 64 + b] : -INFINITY;
    sv[tid] = m; __syncthreads();
    for (int s = 128; s > 0; s >>= 1) {
        if (tid < s) sv[tid] = fmaxf(sv[tid], sv[tid + s]);
        __syncthreads();
    }
    float M = sv[0]; __syncthreads();

    float ssum = (tid < NLB) ? ps[tid * 64 + b] * expf(pm[tid * 64 + b] - M) : 0.f;
    sv[tid] = ssum; __syncthreads();
    for (int s = 128; s > 0; s >>= 1) {
        if (tid < s) sv[tid] += sv[tid + s];
        __syncthreads();
    }
    float lse = M + logf(sv[0]); __syncthreads();

    float bs = -INFINITY; int bi = 0x7fffffff; float bl = 0.f;
    if (tid < NLB) { bs = as_[tid * 64 + b]; bi = ai[tid * 64 + b]; bl = al[tid * 64 + b]; }
    sv[tid] = bs; si_[tid] = bi; sl[tid] = bl; __syncthreads();
    for (int s = 128; s > 0; s >>= 1) {
        if (tid < s) {
            float ov = sv[tid + s]; int oi = si_[tid + s];
            if (ov > sv[tid] || (ov == sv[tid] && oi < si_[tid])) {
                sv[tid] = ov; si_[tid] = oi; sl[tid] = sl[tid + s];
            }
        }
        __syncthreads();
    }
    int sampled = si_[0];
    if (tid == 0) {
        const float LOGV = logf(32000.0f);
        float lp = sl[0] - lse;
        bool draw = eps[t * 64 + b] <= 0.5f;
        float bsv = draw ? -LOGV : lp;
        float off = fminf(fmaxf(expf(bsv), 0.001f), 1.0f);
        out[b * SEQL + t] = (float)sampled;
        out[4096 + b * SEQL + t] = expf(lp) / off;
        out[8192 + b * SEQL + t] = lp;
    }
    const float* er = emb + (size_t)sampled * EMBD;
    for (int k = tid; k < EMBD; k += 256) {
        u16 h_, l_; split_scalar(er[k], h_, l_);
        xhi[b * EMBD + k] = h_; xlo[b * EMBD + k] = l_;
    }
}

extern "C" void kernel_launch(void* const* d_in, const int* in_sizes, int n_in,
                              void* d_out, int out_size, void* d_ws, size_t ws_size,
                              hipStream_t stream) {
    const float* emb   = (const float*)d_in[0];
    const float* w_ih  = (const float*)d_in[1];
    const float* w_hh  = (const float*)d_in[2];
    const float* b_ih  = (const float*)d_in[3];
    const float* b_hh  = (const float*)d_in[4];
    const float* w_out = (const float*)d_in[5];
    const float* b_out = (const float*)d_in[6];
    const float* gum   = (const float*)d_in[7];
    const float* eps   = (const float*)d_in[8];
    float* out = (float*)d_out;
    float* ws  = (float*)d_ws;

    float* H0  = ws;
    float* H1  = ws + 65536;
    float* GI  = ws + 131072;
    float* GH  = ws + 327680;
    float* PM  = ws + 524288;
    float* PS  = ws + 540288;
    float* AS_ = ws + 556288;
    float* AL  = ws + 572288;
    int*   AI  = (int*)(ws + 588288);
    u16*   HHI = (u16*)(ws + 604288);
    u16*   HLO = (u16*)(ws + 637056);
    u16*   XHI = (u16*)(ws + 669824);
    u16*   XLO = (u16*)(ws + 686208);

    k_init<<<64, 256, 0, stream>>>(emb, H0, HHI, HLO, XHI, XLO);
    for (int t = 0; t < SEQL; ++t) {
        float* hin  = (t & 1) ? H1 : H0;
        float* hout = (t & 1) ? H0 : H1;
        k_gates<<<dim3(NGB, 2), 256, 0, stream>>>(w_ih, b_ih, XHI, XLO, GI,
                                                  w_hh, b_hh, HHI, HLO, GH);
        k_gru<<<256, 256, 0, stream>>>(GI, GH, hin, hout, HHI, HLO);
        k_logits<<<NLB, 256, 0, stream>>>(w_out, b_out, HHI, HLO, gum, eps,
                                          PM, PS, AS_, AI, AL, t);
        k_sample<<<64, 256, 0, stream>>>(PM, PS, AS_, AI, AL, emb, eps,
                                         XHI, XLO, out, t);
    }
}

// Round 2
// 6261.562 us; speedup vs baseline: 2.0855x; 1.1141x over previous
//
#include <hip/hip_runtime.h>
#include <math.h>

// Round 2: pre-split MFMA-tiled bf16 hi/lo weights (one-time pass), deeper A
// prefetch (2 chunks ahead), fused gates+GRU kernel (3 kernels/step).
// Numerically bit-identical to round 1.

#define EMBD 512
#define HIDD 1024
#define NVOC 32000
#define SEQL 64
#define NLB  250     // 32000/128 logits blocks

typedef unsigned int   uint32;
typedef unsigned short u16;
typedef __attribute__((ext_vector_type(8))) short bf16x8;   // 8 bf16 (4 VGPR)
typedef __attribute__((ext_vector_type(4))) float f32x4;

// ---- fp32 -> (bf16 hi RNE, bf16 lo trunc) split ------------------------
__device__ __forceinline__ void split_pair(float x, float y, uint32& hi, uint32& lo) {
    uint32 a = __float_as_uint(x), b = __float_as_uint(y);
    uint32 ra = a + 0x7fffu + ((a >> 16) & 1u);
    uint32 rb = b + 0x7fffu + ((b >> 16) & 1u);
    hi = (ra >> 16) | (rb & 0xffff0000u);
    float lx = x - __uint_as_float(ra & 0xffff0000u);
    float ly = y - __uint_as_float(rb & 0xffff0000u);
    lo = (__float_as_uint(lx) >> 16) | (__float_as_uint(ly) & 0xffff0000u);
}

__device__ __forceinline__ void split8(const float4 f0, const float4 f1,
                                       bf16x8& hi, bf16x8& lo) {
    union { bf16x8 v; uint32 u[4]; } H, L;
    split_pair(f0.x, f0.y, H.u[0], L.u[0]);
    split_pair(f0.z, f0.w, H.u[1], L.u[1]);
    split_pair(f1.x, f1.y, H.u[2], L.u[2]);
    split_pair(f1.z, f1.w, H.u[3], L.u[3]);
    hi = H.v; lo = L.v;
}

__device__ __forceinline__ void split_scalar(float f, u16& hi, u16& lo) {
    uint32 u = __float_as_uint(f);
    uint32 r = u + 0x7fffu + ((u >> 16) & 1u);
    hi = (u16)(r >> 16);
    float lf = f - __uint_as_float(r & 0xffff0000u);
    uint32 ul = __float_as_uint(lf);
    uint32 rl = ul + 0x7fffu + ((ul >> 16) & 1u);
    lo = (u16)(rl >> 16);
}

// ---- B fragments: lane l holds B[k=(l>>4)*8+e][col=l&15], stored [b][K] --
__device__ __forceinline__ void load_b4(const u16* __restrict__ Bh,
                                        const u16* __restrict__ Bl,
                                        int K, int kk, int ll,
                                        bf16x8* bh, bf16x8* bl) {
#pragma unroll
    for (int tc = 0; tc < 4; ++tc) {
        size_t off = (size_t)(tc * 16 + ll) * K + kk;
        bh[tc] = *(const bf16x8*)(Bh + off);
        bl[tc] = *(const bf16x8*)(Bl + off);
    }
}

// D += Ahi*Bhi + Ahi*Blo + Alo*Bhi over 4 col tiles
__device__ __forceinline__ void mfma3x4(const bf16x8 ahi, const bf16x8 alo,
                                        const bf16x8* bh, const bf16x8* bl,
                                        f32x4* acc) {
#pragma unroll
    for (int tc = 0; tc < 4; ++tc)
        acc[tc] = __builtin_amdgcn_mfma_f32_16x16x32_bf16(ahi, bh[tc], acc[tc], 0, 0, 0);
#pragma unroll
    for (int tc = 0; tc < 4; ++tc)
        acc[tc] = __builtin_amdgcn_mfma_f32_16x16x32_bf16(ahi, bl[tc], acc[tc], 0, 0, 0);
#pragma unroll
    for (int tc = 0; tc < 4; ++tc)
        acc[tc] = __builtin_amdgcn_mfma_f32_16x16x32_bf16(alo, bh[tc], acc[tc], 0, 0, 0);
}

// ---- weight pre-split into MFMA-lane-linear tiles ----------------------
// layout: off(tile,chunk,lane,e) = (tile*(K/32)+chunk)*512 + lane*8 + e
// where tile = row/16, lane = (k_octet_in_chunk<<4) | (row&15)
__global__ __launch_bounds__(256) void k_split_w(const float* __restrict__ W,
                                                 u16* __restrict__ hi,
                                                 u16* __restrict__ lo,
                                                 int K, int kol2, int total) {
    int idx = blockIdx.x * 256 + threadIdx.x;
    if (idx >= total) return;
    int row = idx >> kol2;                 // kol2 = log2(K/8)
    int ko  = idx & ((1 << kol2) - 1);
    const float* src = W + (size_t)row * K + ko * 8;
    float4 f0 = *(const float4*)src;
    float4 f1 = *(const float4*)(src + 4);
    union { bf16x8 v; uint32 u[4]; } H, L;
    split_pair(f0.x, f0.y, H.u[0], L.u[0]);
    split_pair(f0.z, f0.w, H.u[1], L.u[1]);
    split_pair(f1.x, f1.y, H.u[2], L.u[2]);
    split_pair(f1.z, f1.w, H.u[3], L.u[3]);
    int tile = row >> 4, chunk = ko >> 2;
    int lane = ((ko & 3) << 4) | (row & 15);
    size_t off = ((size_t)tile * (K >> 5) + chunk) * 512 + lane * 8;
    *(bf16x8*)(hi + off) = H.v;
    *(bf16x8*)(lo + off) = L.v;
}

// ---- pipelined GEMM, 1 row-tile (16 rows) x 64 cols, K = NC*32 ---------
template<int NC, bool PS>
__device__ __forceinline__ void gemm_rt1(
    const u16* __restrict__ ah_base, const u16* __restrict__ al_base,
    const float* __restrict__ wrow,
    const u16* __restrict__ bh, const u16* __restrict__ bl,
    int K, int l, int lg, int ll, f32x4* acc) {
    bf16x8 AH[4], AL[4];
    float4 F0[4], F1[4];
    bf16x8 BH[2][4], BL[2][4];
    const int la = l * 8, kl = lg * 8;
#define LA1(c, s) do { if constexpr (PS) { \
        AH[s] = *(const bf16x8*)(ah_base + (size_t)(c) * 512 + la); \
        AL[s] = *(const bf16x8*)(al_base + (size_t)(c) * 512 + la); \
    } else { \
        F0[s] = *(const float4*)(wrow + (c) * 32 + kl); \
        F1[s] = *(const float4*)(wrow + (c) * 32 + kl + 4); } } while (0)
    LA1(0, 0); load_b4(bh, bl, K, kl, ll, BH[0], BL[0]); LA1(1, 1);
#pragma unroll 4
    for (int c = 0; c < NC; ++c) {
        if (c + 1 < NC) load_b4(bh, bl, K, (c + 1) * 32 + kl, ll, BH[(c + 1) & 1], BL[(c + 1) & 1]);
        if (c + 2 < NC) LA1(c + 2, (c + 2) & 3);
        bf16x8 ah, al;
        if constexpr (PS) { ah = AH[c & 3]; al = AL[c & 3]; }
        else split8(F0[c & 3], F1[c & 3], ah, al);
        mfma3x4(ah, al, BH[c & 1], BL[c & 1], acc);
    }
#undef LA1
}

// ---- pipelined GEMM, 2 row-tiles sharing B -----------------------------
template<int NC, bool PS>
__device__ __forceinline__ void gemm_rt2(
    const u16* __restrict__ ah0, const u16* __restrict__ al0,
    const u16* __restrict__ ah1, const u16* __restrict__ al1,
    const float* __restrict__ wrow0, const float* __restrict__ wrow1,
    const u16* __restrict__ bh, const u16* __restrict__ bl,
    int K, int l, int lg, int ll, f32x4* acc0, f32x4* acc1) {
    bf16x8 AH[4][2], AL[4][2];
    float4 F[4][2][2];
    bf16x8 BH[2][4], BL[2][4];
    const int la = l * 8, kl = lg * 8;
#define LA2(c, s) do { if constexpr (PS) { \
        AH[s][0] = *(const bf16x8*)(ah0 + (size_t)(c) * 512 + la); \
        AL[s][0] = *(const bf16x8*)(al0 + (size_t)(c) * 512 + la); \
        AH[s][1] = *(const bf16x8*)(ah1 + (size_t)(c) * 512 + la); \
        AL[s][1] = *(const bf16x8*)(al1 + (size_t)(c) * 512 + la); \
    } else { \
        F[s][0][0] = *(const float4*)(wrow0 + (c) * 32 + kl); \
        F[s][0][1] = *(const float4*)(wrow0 + (c) * 32 + kl + 4); \
        F[s][1][0] = *(const float4*)(wrow1 + (c) * 32 + kl); \
        F[s][1][1] = *(const float4*)(wrow1 + (c) * 32 + kl + 4); } } while (0)
    LA2(0, 0); load_b4(bh, bl, K, kl, ll, BH[0], BL[0]); LA2(1, 1);
#pragma unroll 4
    for (int c = 0; c < NC; ++c) {
        if (c + 1 < NC) load_b4(bh, bl, K, (c + 1) * 32 + kl, ll, BH[(c + 1) & 1], BL[(c + 1) & 1]);
        if (c + 2 < NC) LA2(c + 2, (c + 2) & 3);
        bf16x8 ah, al;
        if constexpr (PS) { ah = AH[c & 3][0]; al = AL[c & 3][0]; }
        else split8(F[c & 3][0][0], F[c & 3][0][1], ah, al);
        mfma3x4(ah, al, BH[c & 1], BL[c & 1], acc0);
        if constexpr (PS) { ah = AH[c & 3][1]; al = AL[c & 3][1]; }
        else split8(F[c & 3][1][0], F[c & 3][1][1], ah, al);
        mfma3x4(ah, al, BH[c & 1], BL[c & 1], acc1);
    }
#undef LA2
}

// ---- init: h=0, x = emb[0] (split) -------------------------------------
__global__ __launch_bounds__(256) void k_init(const float* __restrict__ emb,
                                              float* __restrict__ h0,
                                              u16* __restrict__ hhi, u16* __restrict__ hlo,
                                              u16* __restrict__ xhi, u16* __restrict__ xlo) {
    int b = blockIdx.x, tid = threadIdx.x;
    for (int j = tid; j < HIDD; j += 256) {
        h0[b * HIDD + j] = 0.f; hhi[b * HIDD + j] = 0; hlo[b * HIDD + j] = 0;
    }
    for (int k = tid; k < EMBD; k += 256) {
        u16 h_, l_; split_scalar(emb[k], h_, l_);
        xhi[b * EMBD + k] = h_; xlo[b * EMBD + k] = l_;
    }
}

// ---- fused gates + GRU: 64 blocks x 384 thr (6 waves) ------------------
// block bx owns j-range [bx*16, bx*16+16); wave w<3 -> W_ih gate w, w>=3 -> W_hh gate w-3
template<bool PS>
__global__ __launch_bounds__(384) void k_gateru(
    const float* __restrict__ w_ih, const float* __restrict__ b_ih,
    const float* __restrict__ w_hh, const float* __restrict__ b_hh,
    const u16* __restrict__ wihhi, const u16* __restrict__ wihlo,
    const u16* __restrict__ whhhi, const u16* __restrict__ whhlo,
    const u16* __restrict__ xhi, const u16* __restrict__ xlo,
    const u16* __restrict__ bhin, const u16* __restrict__ blin,
    const float* __restrict__ h_in, float* __restrict__ h_out,
    u16* __restrict__ bhout, u16* __restrict__ blout) {
    __shared__ float G[6][16][64];
    const int tid = threadIdx.x, wv = tid / 64, l = tid & 63, lg = l >> 4, ll = l & 15;
    const int j0 = blockIdx.x * 16;
    const int g = (wv < 3) ? wv : wv - 3;
    const int tile = g * 64 + blockIdx.x;          // row-tile in the 3072-row matrix
    f32x4 acc[4] = {};
    if (wv < 3) {
        gemm_rt1<16, PS>(wihhi + (size_t)tile * 16 * 512, wihlo + (size_t)tile * 16 * 512,
                         w_ih + (size_t)(tile * 16 + ll) * EMBD,
                         xhi, xlo, EMBD, l, lg, ll, acc);
    } else {
        gemm_rt1<32, PS>(whhhi + (size_t)tile * 32 * 512, whhlo + (size_t)tile * 32 * 512,
                         w_hh + (size_t)(tile * 16 + ll) * HIDD,
                         bhin, blin, HIDD, l, lg, ll, acc);
    }
    const float* bias = (wv < 3) ? b_ih : b_hh;
    const int rowbase = g * 1024 + j0;
#pragma unroll
    for (int j = 0; j < 4; ++j) {
        float bi = bias[rowbase + lg * 4 + j];
#pragma unroll
        for (int tc = 0; tc < 4; ++tc)
            G[wv][lg * 4 + j][tc * 16 + ll] = acc[tc][j] + bi;
    }
    __syncthreads();
    for (int e = tid; e < 1024; e += 384) {
        int j = e >> 6, b = e & 63, jg = j0 + j;
        float ir = G[0][j][b], iz = G[1][j][b], in_ = G[2][j][b];
        float hr = G[3][j][b], hz = G[4][j][b], hn = G[5][j][b];
        float h = h_in[b * HIDD + jg];
        float r = 1.f / (1.f + expf(-(ir + hr)));
        float z = 1.f / (1.f + expf(-(iz + hz)));
        float n = tanhf(in_ + r * hn);
        float hnew = (1.f - z) * n + z * h;
        h_out[b * HIDD + jg] = hnew;
        u16 h_, l_; split_scalar(hnew, h_, l_);
        bhout[b * HIDD + jg] = h_; blout[b * HIDD + jg] = l_;
    }
}

// ---- logits GEMM + fused softmax/argmax partials -----------------------
template<bool PS>
__global__ __launch_bounds__(256) void k_logits(
    const float* __restrict__ w_out, const float* __restrict__ b_out,
    const u16* __restrict__ wohi, const u16* __restrict__ wolo,
    const u16* __restrict__ hhi, const u16* __restrict__ hlo,
    const float* __restrict__ gum, const float* __restrict__ eps,
    float* __restrict__ pm, float* __restrict__ ps,
    float* __restrict__ as_, int* __restrict__ ai, float* __restrict__ al,
    int t) {
    const int tid = threadIdx.x, wv = tid >> 6, l = tid & 63, lg = l >> 4, ll = l & 15;
    const int rb = blockIdx.x * 128 + wv * 32;
    const size_t T0 = (size_t)(rb >> 4);
    f32x4 acc[2][4] = {};
    gemm_rt2<32, PS>(wohi + T0 * 32 * 512, wolo + T0 * 32 * 512,
                     wohi + (T0 + 1) * 32 * 512, wolo + (T0 + 1) * 32 * 512,
                     w_out + (size_t)(rb + ll) * HIDD, w_out + (size_t)(rb + 16 + ll) * HIDD,
                     hhi, hlo, HIDD, l, lg, ll, acc[0], acc[1]);

    float val[2][4][4];
#pragma unroll
    for (int tr = 0; tr < 2; ++tr)
#pragma unroll
        for (int j = 0; j < 4; ++j) {
            float bo = b_out[rb + tr * 16 + lg * 4 + j];
#pragma unroll
            for (int tc = 0; tc < 4; ++tc) val[tr][tc][j] = acc[tr][tc][j] + bo;
        }

    bool draw[4];
    float4 g4[2][4];
#pragma unroll
    for (int tc = 0; tc < 4; ++tc) {
        int b = tc * 16 + ll;
        draw[tc] = eps[t * 64 + b] <= 0.5f;
#pragma unroll
        for (int tr = 0; tr < 2; ++tr)
            g4[tr][tc] = *(const float4*)(gum + ((size_t)t * 64 + b) * NVOC + rb + tr * 16 + lg * 4);
    }

    __shared__ float sred[4][64];
    __shared__ float sred2[4][64];
    __shared__ int   sredi[4][64];
    __shared__ float sbm[64];

    float lm[4];
#pragma unroll
    for (int tc = 0; tc < 4; ++tc) {
        float m = val[0][tc][0];
#pragma unroll
        for (int tr = 0; tr < 2; ++tr)
#pragma unroll
            for (int j = 0; j < 4; ++j) m = fmaxf(m, val[tr][tc][j]);
        m = fmaxf(m, __shfl_xor(m, 16));
        m = fmaxf(m, __shfl_xor(m, 32));
        lm[tc] = m;
    }
    if (l < 16) {
#pragma unroll
        for (int tc = 0; tc < 4; ++tc) sred[wv][tc * 16 + l] = lm[tc];
    }
    __syncthreads();
    if (tid < 64) {
        float m = fmaxf(fmaxf(sred[0][tid], sred[1][tid]), fmaxf(sred[2][tid], sred[3][tid]));
        sbm[tid] = m;
        pm[blockIdx.x * 64 + tid] = m;
    }
    __syncthreads();

#pragma unroll
    for (int tc = 0; tc < 4; ++tc) {
        float bm = sbm[tc * 16 + ll];
        float s = 0.f;
#pragma unroll
        for (int tr = 0; tr < 2; ++tr)
#pragma unroll
            for (int j = 0; j < 4; ++j) s += expf(val[tr][tc][j] - bm);
        s += __shfl_xor(s, 16);
        s += __shfl_xor(s, 32);
        lm[tc] = s;
    }
    if (l < 16) {
#pragma unroll
        for (int tc = 0; tc < 4; ++tc) sred[wv][tc * 16 + l] = lm[tc];
    }
    __syncthreads();
    if (tid < 64)
        ps[blockIdx.x * 64 + tid] = sred[0][tid] + sred[1][tid] + sred[2][tid] + sred[3][tid];

    const float LOGV = logf(32000.0f);
    float bsc[4]; int bix[4]; float blg[4];
#pragma unroll
    for (int tc = 0; tc < 4; ++tc) {
        float bs = -INFINITY; int bi = 0x7fffffff; float bl = 0.f;
#pragma unroll
        for (int tr = 0; tr < 2; ++tr) {
            const float* gp = (const float*)&g4[tr][tc];
#pragma unroll
            for (int j = 0; j < 4; ++j) {
                float u = fminf(fmaxf(gp[j], 1e-12f), 1.0f);
                float g = -logf(-logf(u));
                float sc = draw[tc] ? (g - LOGV) : (val[tr][tc][j] + g);
                if (sc > bs) { bs = sc; bi = rb + tr * 16 + lg * 4 + j; bl = val[tr][tc][j]; }
            }
        }
#pragma unroll
        for (int m2 = 16; m2 <= 32; m2 <<= 1) {
            float os = __shfl_xor(bs, m2);
            int   oi = __shfl_xor(bi, m2);
            float ol = __shfl_xor(bl, m2);
            if (os > bs || (os == bs && oi < bi)) { bs = os; bi = oi; bl = ol; }
        }
        bsc[tc] = bs; bix[tc] = bi; blg[tc] = bl;
    }
    __syncthreads();
    if (l < 16) {
#pragma unroll
        for (int tc = 0; tc < 4; ++tc) {
            sred[wv][tc * 16 + l]  = bsc[tc];
            sredi[wv][tc * 16 + l] = bix[tc];
            sred2[wv][tc * 16 + l] = blg[tc];
        }
    }
    __syncthreads();
    if (tid < 64) {
        float bs = sred[0][tid]; int bi = sredi[0][tid]; float bl = sred2[0][tid];
#pragma unroll
        for (int w2 = 1; w2 < 4; ++w2) {
            float os = sred[w2][tid]; int oi = sredi[w2][tid];
            if (os > bs || (os == bs && oi < bi)) { bs = os; bi = oi; bl = sred2[w2][tid]; }
        }
        as_[blockIdx.x * 64 + tid] = bs;
        ai[blockIdx.x * 64 + tid]  = bi;
        al[blockIdx.x * 64 + tid]  = bl;
    }
}

// ---- final reduce over 250 partials + outputs + emb gather/split -------
__global__ __launch_bounds__(256) void k_sample(
    const float* __restrict__ pm, const float* __restrict__ ps,
    const float* __restrict__ as_, const int* __restrict__ ai, const float* __restrict__ al,
    const float* __restrict__ emb, const float* __restrict__ eps,
    u16* __restrict__ xhi, u16* __restrict__ xlo,
    float* __restrict__ out, int t) {
    int b = blockIdx.x, tid = threadIdx.x;
    __shared__ float sv[256];
    __shared__ int   si_[256];
    __shared__ float sl[256];

    float m = (tid < NLB) ? pm[tid * 64 + b] : -INFINITY;
    sv[tid] = m; __syncthreads();
    for (int s = 128; s > 0; s >>= 1) {
        if (tid < s) sv[tid] = fmaxf(sv[tid], sv[tid + s]);
        __syncthreads();
    }
    float M = sv[0]; __syncthreads();

    float ssum = (tid < NLB) ? ps[tid * 64 + b] * expf(pm[tid * 64 + b] - M) : 0.f;
    sv[tid] = ssum; __syncthreads();
    for (int s = 128; s > 0; s >>= 1) {
        if (tid < s) sv[tid] += sv[tid + s];
        __syncthreads();
    }
    float lse = M + logf(sv[0]); __syncthreads();

    float bs = -INFINITY; int bi = 0x7fffffff; float bl = 0.f;
    if (tid < NLB) { bs = as_[tid * 64 + b]; bi = ai[tid * 64 + b]; bl = al[tid * 64 + b]; }
    sv[tid] = bs; si_[tid] = bi; sl[tid] = bl; __syncthreads();
    for (int s = 128; s > 0; s >>= 1) {
        if (tid < s) {
            float ov = sv[tid + s]; int oi = si_[tid + s];
            if (ov > sv[tid] || (ov == sv[tid] && oi < si_[tid])) {
                sv[tid] = ov; si_[tid] = oi; sl[tid] = sl[tid + s];
            }
        }
        __syncthreads();
    }
    int sampled = si_[0];
    if (tid == 0) {
        const float LOGV = logf(32000.0f);
        float lp = sl[0] - lse;
        bool draw = eps[t * 64 + b] <= 0.5f;
        float bsv = draw ? -LOGV : lp;
        float off = fminf(fmaxf(expf(bsv), 0.001f), 1.0f);
        out[b * SEQL + t] = (float)sampled;
        out[4096 + b * SEQL + t] = expf(lp) / off;
        out[8192 + b * SEQL + t] = lp;
    }
    const float* er = emb + (size_t)sampled * EMBD;
    for (int k = tid; k < EMBD; k += 256) {
        u16 h_, l_; split_scalar(er[k], h_, l_);
        xhi[b * EMBD + k] = h_; xlo[b * EMBD + k] = l_;
    }
}

extern "C" void kernel_launch(void* const* d_in, const int* in_sizes, int n_in,
                              void* d_out, int out_size, void* d_ws, size_t ws_size,
                              hipStream_t stream) {
    const float* emb   = (const float*)d_in[0];
    const float* w_ih  = (const float*)d_in[1];
    const float* w_hh  = (const float*)d_in[2];
    const float* b_ih  = (const float*)d_in[3];
    const float* b_hh  = (const float*)d_in[4];
    const float* w_out = (const float*)d_in[5];
    const float* b_out = (const float*)d_in[6];
    const float* gum   = (const float*)d_in[7];
    const float* eps   = (const float*)d_in[8];
    float* out = (float*)d_out;
    char*  w8  = (char*)d_ws;

    // byte offsets
    float* H[2]   = { (float*)(w8 + 0),       (float*)(w8 + 262144) };
    float* PM     = (float*)(w8 + 524288);
    float* PSUM   = (float*)(w8 + 589824);
    float* AS_    = (float*)(w8 + 655360);
    float* AL     = (float*)(w8 + 720896);
    int*   AI     = (int*)  (w8 + 786432);
    u16*   HSH[2] = { (u16*)(w8 + 851968),    (u16*)(w8 + 1114112) };
    u16*   HSL[2] = { (u16*)(w8 + 983040),    (u16*)(w8 + 1245184) };
    u16*   XHI    = (u16*)(w8 + 1376256);
    u16*   XLO    = (u16*)(w8 + 1441792);
    u16*   WIHHI  = (u16*)(w8 + 2097152);
    u16*   WIHLO  = (u16*)(w8 + 5242880);
    u16*   WHHHI  = (u16*)(w8 + 8388608);
    u16*   WHHLO  = (u16*)(w8 + 14680064);
    u16*   WOHI   = (u16*)(w8 + 20971520);
    u16*   WOLO   = (u16*)(w8 + 86507520);

    const size_t NEED_GATES = 20971520;
    const size_t NEED_FULL  = 152043520;
    const bool psg = ws_size >= NEED_GATES;
    const bool psl = ws_size >= NEED_FULL;

    if (psg) {
        k_split_w<<<768,  256, 0, stream>>>(w_ih, WIHHI, WIHLO, EMBD, 6, 3072 * (EMBD / 8));
        k_split_w<<<1536, 256, 0, stream>>>(w_hh, WHHHI, WHHLO, HIDD, 7, 3072 * (HIDD / 8));
    }
    if (psl) {
        k_split_w<<<16000, 256, 0, stream>>>(w_out, WOHI, WOLO, HIDD, 7, NVOC * (HIDD / 8));
    }
    k_init<<<64, 256, 0, stream>>>(emb, H[0], HSH[0], HSL[0], XHI, XLO);

    for (int t = 0; t < SEQL; ++t) {
        const int hi_ = t & 1, ho_ = (t + 1) & 1;
        if (psg)
            k_gateru<true><<<64, 384, 0, stream>>>(w_ih, b_ih, w_hh, b_hh,
                WIHHI, WIHLO, WHHHI, WHHLO, XHI, XLO,
                HSH[hi_], HSL[hi_], H[hi_], H[ho_], HSH[ho_], HSL[ho_]);
        else
            k_gateru<false><<<64, 384, 0, stream>>>(w_ih, b_ih, w_hh, b_hh,
                WIHHI, WIHLO, WHHHI, WHHLO, XHI, XLO,
                HSH[hi_], HSL[hi_], H[hi_], H[ho_], HSH[ho_], HSL[ho_]);
        if (psl)
            k_logits<true><<<NLB, 256, 0, stream>>>(w_out, b_out, WOHI, WOLO,
                HSH[ho_], HSL[ho_], gum, eps, PM, PSUM, AS_, AI, AL, t);
        else
            k_logits<false><<<NLB, 256, 0, stream>>>(w_out, b_out, WOHI, WOLO,
                HSH[ho_], HSL[ho_], gum, eps, PM, PSUM, AS_, AI, AL, t);
        k_sample<<<64, 256, 0, stream>>>(PM, PSUM, AS_, AI, AL, emb, eps,
                                         XHI, XLO, out, t);
    }
}